// Round 4
// baseline (459.689 us; speedup 1.0000x reference)
//
#include <hip/hip_runtime.h>
#include <stdint.h>

namespace {

typedef __attribute__((ext_vector_type(8)))  short short8;   // 8 bf16
typedef __attribute__((ext_vector_type(16))) float f32x16;
typedef __attribute__((ext_vector_type(4)))  float f32x4;

union U4 {
    uint4    q;
    uint32_t u[4];
    uint16_t us[8];
    short8   s8;
};

constexpr float INV_SCALE = 0.08838834764831845f;  // 1/sqrt(128), BOTH attn blocks

// ---- workspace (weight fragment) layout, bytes ----
// per proj matrix: frags[(c*8+kb)*2 + hiLo][lane] of 16B; c=0..3, kb=0..7
constexpr size_t WSPROJ = 65536;            // 4*8*2*1024
constexpr size_t WP1OFF = 6 * WSPROJ;       // Wp1: c=0..7, kb=0..7 -> 131072 B
constexpr size_t WP2OFF = WP1OFF + 131072;  // Wp2 (16x16 frags): kb=0..7 -> 16384 B

// ---- LDS arena (53760 B -> 3 blocks/CU) ----
constexpr int K_OFF = 0;       // packed {hi|lo} u32 [32][128], swizzled, 16KB
constexpr int Q_OFF = 16384;   // packed {hi|lo} u32 [32][128], swizzled, 16KB
constexpr int V_OFF = 32768;   // VT packed u32 [128e][32m], swizzled, 16KB
constexpr int S_OFF = 49152;   // fp32 [32][36dw], 4608B
// ACT fp32 [32][128] (swizzled) aliases [0,16384)     = K region (dead when written)
// H   bf16 [32][256] (swizzled) aliases [16384,32768) = Q region (dead when written)

__device__ __forceinline__ int qk_addr(int base, int m, int e) {
    return base + ((m * 512 + e * 4) ^ ((m & 31) << 4));
}
__device__ __forceinline__ int vt_addr(int e, int m) {
    return V_OFF + ((e * 128 + m * 4) ^ ((e & 7) << 4));
}
__device__ __forceinline__ int s_addr(int n, int m) {
    return S_OFF + n * 144 + m * 4;
}
__device__ __forceinline__ int act_addr(int n, int d) {
    return ((n * 512 + d * 4) ^ ((n & 31) << 4));
}
__device__ __forceinline__ int h_addr(int n, int h) {
    return Q_OFF + ((n * 512 + h * 2) ^ ((n & 15) << 4));
}

__device__ __forceinline__ uint16_t f2bf_rne(float x) {  // round-to-nearest-even bf16
    uint32_t u = __float_as_uint(x);
    u += 0x7FFFu + ((u >> 16) & 1u);
    return (uint16_t)(u >> 16);
}

// split 8 fp32 -> (hi bf16x8, lo bf16x8); hi = trunc, lo = trunc(x - hi)
__device__ __forceinline__ void split8(float4 a, float4 b, short8& hi, short8& lo) {
    float xs[8] = {a.x, a.y, a.z, a.w, b.x, b.y, b.z, b.w};
    U4 h, l;
#pragma unroll
    for (int p = 0; p < 4; ++p) {
        uint32_t b0 = __float_as_uint(xs[2 * p]);
        uint32_t b1 = __float_as_uint(xs[2 * p + 1]);
        float r0 = xs[2 * p]     - __uint_as_float(b0 & 0xFFFF0000u);
        float r1 = xs[2 * p + 1] - __uint_as_float(b1 & 0xFFFF0000u);
        h.u[p] = __builtin_amdgcn_perm(b1, b0, 0x07060302u);                       // [hi(x1)|hi(x0)]
        l.u[p] = __builtin_amdgcn_perm(__float_as_uint(r1), __float_as_uint(r0), 0x07060302u);
    }
    hi = h.s8; lo = l.s8;
}

// 8 packed dwords {hi16|lo16} -> hi frag / lo frag
__device__ __forceinline__ void unpack8(const uint32_t* d, short8& hi, short8& lo) {
    U4 h, l;
#pragma unroll
    for (int p = 0; p < 4; ++p) {
        h.u[p] = __builtin_amdgcn_perm(d[2 * p + 1], d[2 * p], 0x07060302u);
        l.u[p] = __builtin_amdgcn_perm(d[2 * p + 1], d[2 * p], 0x05040100u);
    }
    hi = h.s8; lo = l.s8;
}

__device__ __forceinline__ uint32_t pack_hilo(float x) {
    uint32_t b = __float_as_uint(x);
    float r = x - __uint_as_float(b & 0xFFFF0000u);
    return __builtin_amdgcn_perm(b, __float_as_uint(r), 0x07060302u);  // [hi(x)|hi(r)]
}

// 32x128 GEMM col-tile c (K=128): acc[n][e] = sum_d A[n][d] * W[e][d], 3-term split
__device__ __forceinline__ f32x16 gemm32(const uint8_t* __restrict__ matbase, int c, int l,
                                         const short8* ahi, const short8* alo) {
    f32x16 acc = {0.f,0.f,0.f,0.f, 0.f,0.f,0.f,0.f, 0.f,0.f,0.f,0.f, 0.f,0.f,0.f,0.f};
#pragma unroll
    for (int kb = 0; kb < 8; ++kb) {
        const uint8_t* p = matbase + (size_t)((c * 8 + kb) * 2) * 1024 + (size_t)l * 16;
        U4 bh, bl;
        bh.q = *(const uint4*)p;
        bl.q = *(const uint4*)(p + 1024);
        acc = __builtin_amdgcn_mfma_f32_32x32x16_bf16(ahi[kb], bh.s8, acc, 0, 0, 0);
        acc = __builtin_amdgcn_mfma_f32_32x32x16_bf16(alo[kb], bh.s8, acc, 0, 0, 0);
        acc = __builtin_amdgcn_mfma_f32_32x32x16_bf16(ahi[kb], bl.s8, acc, 0, 0, 0);
    }
    return acc;
}

__device__ __forceinline__ void store_qk(char* smem, int base, int c, int l, const f32x16& acc) {
    const int e = c * 32 + (l & 31);
    const int half = l >> 5;
#pragma unroll
    for (int r = 0; r < 16; ++r) {
        int n = (r & 3) + 8 * (r >> 2) + 4 * half;   // verified 32x32 D mapping
        *(uint32_t*)(smem + qk_addr(base, n, e)) = pack_hilo(acc[r]);
    }
}

// -------- pre-pass: convert weights to fragment-ordered split-bf16 in d_ws --------
__global__ void prepack(const float* __restrict__ Wk1, const float* __restrict__ Wq1,
                        const float* __restrict__ Wv1, const float* __restrict__ Wk2,
                        const float* __restrict__ Wq2, const float* __restrict__ Wv2,
                        const float* __restrict__ Wp1, const float* __restrict__ Wp2,
                        uint8_t* __restrict__ wsb) {
    const int bid = blockIdx.x;
    const int l = threadIdx.x;
    float4 fa = make_float4(0.f, 0.f, 0.f, 0.f), fb = fa;
    uint8_t* dst;
    if (bid < 192) {                       // 6 proj matrices, 32x32 B-frags
        int m = bid >> 5, rem = bid & 31, c = rem >> 3, kb = rem & 7;
        const float* W = (m == 0) ? Wk1 : (m == 1) ? Wq1 : (m == 2) ? Wv1
                       : (m == 3) ? Wk2 : (m == 4) ? Wq2 : Wv2;
        int e  = c * 32 + (l & 31);        // B col on lane&31
        int d0 = kb * 16 + (l >> 5) * 8;   // k = 8*(l>>5)+i
        const float* src = W + e * 128 + d0;
        fa = *(const float4*)src;
        fb = *(const float4*)(src + 4);
        dst = wsb + (size_t)m * WSPROJ + (size_t)((c * 8 + kb) * 2) * 1024 + l * 16;
    } else if (bid < 256) {                // Wp1 [256][128]
        int idx = bid - 192, c = idx >> 3, kb = idx & 7;
        int e  = c * 32 + (l & 31);
        int d0 = kb * 16 + (l >> 5) * 8;
        const float* src = Wp1 + e * 128 + d0;
        fa = *(const float4*)src;
        fb = *(const float4*)(src + 4);
        dst = wsb + WP1OFF + (size_t)((c * 8 + kb) * 2) * 1024 + l * 16;
    } else {                               // Wp2 [10][256] -> 16x16 B-frags, cols 10..15 zero
        int kb = bid - 256;
        int a  = l & 15;
        int h0 = kb * 32 + ((l >> 4) & 3) * 8;
        if (a < 10) {
            const float* src = Wp2 + a * 256 + h0;
            fa = *(const float4*)src;
            fb = *(const float4*)(src + 4);
        }
        dst = wsb + WP2OFF + (size_t)(kb * 2) * 1024 + l * 16;
    }
    short8 hi, lo;
    split8(fa, fb, hi, lo);
    *(short8*)dst = hi;
    *(short8*)(dst + 1024) = lo;
}

// -------- main fused kernel: one batch per block, 4 waves, 3 blocks/CU --------
__global__ __launch_bounds__(256, 3)
void fused_net(const float* __restrict__ states, const uint8_t* __restrict__ wsb,
               float* __restrict__ out_policy, float* __restrict__ out_w1,
               float* __restrict__ out_w2) {
    __shared__ __align__(16) char smem[53760];

    const int b    = blockIdx.x;
    const int t    = threadIdx.x;
    const int w    = t >> 6;
    const int l    = t & 63;
    const int l31  = l & 31;
    const int half = l >> 5;
    const int l15  = l & 15;
    const int g4   = (l >> 4) & 3;

    // ---- A-frags of X straight from global (no staging), split once ----
    short8 ahi[8], alo[8];
    {
        const float* xrow = states + (size_t)b * 4096 + (size_t)l31 * 128;
#pragma unroll
        for (int kb = 0; kb < 8; ++kb) {
            int d0 = kb * 16 + half * 8;
            float4 fa = *(const float4*)(xrow + d0);
            float4 fb = *(const float4*)(xrow + d0 + 4);
            split8(fa, fb, ahi[kb], alo[kb]);
        }
    }

#pragma unroll 1
    for (int blk = 0; blk < 2; ++blk) {
        const uint8_t* wb = wsb + (size_t)(blk * 3) * WSPROJ;

        // ---- projections: wave w owns col-tile c=w of K, Q, V ----
        {
            f32x16 acc = gemm32(wb + 0 * WSPROJ, w, l, ahi, alo);
            store_qk(smem, K_OFF, w, l, acc);
        }
        {
            f32x16 acc = gemm32(wb + 1 * WSPROJ, w, l, ahi, alo);
            store_qk(smem, Q_OFF, w, l, acc);
        }
        {
            f32x16 acc = gemm32(wb + 2 * WSPROJ, w, l, ahi, alo);
            const int e = w * 32 + l31;
#pragma unroll
            for (int r = 0; r < 16; ++r) {
                int m = (r & 3) + 8 * (r >> 2) + 4 * half;
                *(uint32_t*)(smem + vt_addr(e, m)) = pack_hilo(acc[r]);
            }
        }
        __syncthreads();

        // ---- S = (Q K^T)*inv_scale: 4x 16x16 tiles, wave w -> (rb=w>>1, mb=w&1) ----
        {
            f32x4 s4 = {0.f, 0.f, 0.f, 0.f};
            const int rb = w >> 1, mb = w & 1;
            const int qrow = rb * 16 + l15;
            const int krow = mb * 16 + l15;
#pragma unroll
            for (int kb = 0; kb < 4; ++kb) {
                int e0 = kb * 32 + g4 * 8;
                uint32_t qd[8], kd[8];
                *(uint4*)&qd[0] = *(const uint4*)(smem + qk_addr(Q_OFF, qrow, e0));
                *(uint4*)&qd[4] = *(const uint4*)(smem + qk_addr(Q_OFF, qrow, e0 + 4));
                *(uint4*)&kd[0] = *(const uint4*)(smem + qk_addr(K_OFF, krow, e0));
                *(uint4*)&kd[4] = *(const uint4*)(smem + qk_addr(K_OFF, krow, e0 + 4));
                short8 qh, ql, kh, kl;
                unpack8(qd, qh, ql);
                unpack8(kd, kh, kl);
                s4 = __builtin_amdgcn_mfma_f32_16x16x32_bf16(qh, kh, s4, 0, 0, 0);
                s4 = __builtin_amdgcn_mfma_f32_16x16x32_bf16(ql, kh, s4, 0, 0, 0);
                s4 = __builtin_amdgcn_mfma_f32_16x16x32_bf16(qh, kl, s4, 0, 0, 0);
            }
#pragma unroll
            for (int r = 0; r < 4; ++r) {
                int n = rb * 16 + g4 * 4 + r;    // verified 16x16 D mapping
                *(float*)(smem + s_addr(n, krow)) = s4[r] * INV_SCALE;
            }
        }
        __syncthreads();

        // ---- softmax over m (wave 0: lane = row | half) ----
        if (t < 64) {
            const int n = l31;
            float4 v0 = *(const float4*)(smem + s_addr(n, half * 16));
            float4 v1 = *(const float4*)(smem + s_addr(n, half * 16 + 4));
            float4 v2 = *(const float4*)(smem + s_addr(n, half * 16 + 8));
            float4 v3 = *(const float4*)(smem + s_addr(n, half * 16 + 12));
            float vv[16] = {v0.x, v0.y, v0.z, v0.w, v1.x, v1.y, v1.z, v1.w,
                            v2.x, v2.y, v2.z, v2.w, v3.x, v3.y, v3.z, v3.w};
            float mx = vv[0];
#pragma unroll
            for (int i = 1; i < 16; ++i) mx = fmaxf(mx, vv[i]);
            mx = fmaxf(mx, __shfl_xor(mx, 32));
            float sum = 0.f;
#pragma unroll
            for (int i = 0; i < 16; ++i) { vv[i] = __expf(vv[i] - mx); sum += vv[i]; }
            sum += __shfl_xor(sum, 32);
            float inv = 1.0f / sum;
#pragma unroll
            for (int i = 0; i < 16; ++i) vv[i] *= inv;
            *(float4*)(smem + s_addr(n, half * 16))      = make_float4(vv[0], vv[1], vv[2], vv[3]);
            *(float4*)(smem + s_addr(n, half * 16 + 4))  = make_float4(vv[4], vv[5], vv[6], vv[7]);
            *(float4*)(smem + s_addr(n, half * 16 + 8))  = make_float4(vv[8], vv[9], vv[10], vv[11]);
            *(float4*)(smem + s_addr(n, half * 16 + 12)) = make_float4(vv[12], vv[13], vv[14], vv[15]);
        }
        __syncthreads();

        // ---- attention-weight output (coalesced) ----
        {
            float* outw = blk ? out_w2 : out_w1;
            int f = t * 4;
            int n = f >> 5, m0 = f & 31;
            float4 o = *(const float4*)(smem + s_addr(n, m0));
            *(float4*)(outw + (size_t)b * 1024 + f) = o;
        }

        // ---- PV: WAV[n][e] = sum_m P[n][m] V[m][e]; P 2-term, V 2-term, 3 MFMA ----
        {
            f32x16 pv = {0.f,0.f,0.f,0.f, 0.f,0.f,0.f,0.f, 0.f,0.f,0.f,0.f, 0.f,0.f,0.f,0.f};
            const int e = w * 32 + l31;
#pragma unroll
            for (int kb = 0; kb < 2; ++kb) {
                int m0 = kb * 16 + half * 8;
                float4 fa = *(const float4*)(smem + s_addr(l31, m0));
                float4 fb = *(const float4*)(smem + s_addr(l31, m0 + 4));
                short8 wh, wl;
                split8(fa, fb, wh, wl);
                uint32_t vd[8];
                *(uint4*)&vd[0] = *(const uint4*)(smem + vt_addr(e, m0));
                *(uint4*)&vd[4] = *(const uint4*)(smem + vt_addr(e, m0 + 4));
                short8 vh, vl;
                unpack8(vd, vh, vl);
                pv = __builtin_amdgcn_mfma_f32_32x32x16_bf16(wh, vh, pv, 0, 0, 0);
                pv = __builtin_amdgcn_mfma_f32_32x32x16_bf16(wl, vh, pv, 0, 0, 0);
                pv = __builtin_amdgcn_mfma_f32_32x32x16_bf16(wh, vl, pv, 0, 0, 0);
            }
            // ACT store aliases K region (dead since S-phase barrier); disjoint from S/VT,
            // so no barrier needed between PV-MFMA reads and this store.
            const int e2 = w * 32 + l31;
#pragma unroll
            for (int r = 0; r < 16; ++r) {
                int n = (r & 3) + 8 * (r >> 2) + 4 * half;
                *(float*)(smem + act_addr(n, e2)) = pv[r];
            }
        }
        __syncthreads();

        // ---- re-split A-frags from ACT (WAV for blk1 / NF for MLP) ----
#pragma unroll
        for (int kb = 0; kb < 8; ++kb) {
            int d0 = kb * 16 + half * 8;
            float4 fa = *(const float4*)(smem + act_addr(l31, d0));
            float4 fb = *(const float4*)(smem + act_addr(l31, d0 + 4));
            split8(fa, fb, ahi[kb], alo[kb]);
        }
        __syncthreads();   // ACT reads done before next blk's K-writes overwrite [0,16K)
    }

    // ---- MLP hidden: H = leaky_relu(NF @ Wp1^T) -> bf16 rne, aliases Q region ----
#pragma unroll
    for (int rep = 0; rep < 2; ++rep) {
        const int c = w + rep * 4;
        f32x16 acc = gemm32(wsb + WP1OFF, c, l, ahi, alo);
        const int hcol = c * 32 + l31;
#pragma unroll
        for (int r = 0; r < 16; ++r) {
            int n = (r & 3) + 8 * (r >> 2) + 4 * half;
            float x = acc[r];
            x = fmaxf(x, 0.01f * x);                      // leaky_relu
            *(uint16_t*)(smem + h_addr(n, hcol)) = f2bf_rne(x);
        }
    }
    __syncthreads();

    // ---- policy logits: 2x 16x16 tiles (waves 0,1), K=256, A=H(1-term), B=Wp2(hi+lo) ----
    if (w < 2) {
        f32x4 acc = {0.f, 0.f, 0.f, 0.f};
        const int n = w * 16 + l15;
#pragma unroll
        for (int kb = 0; kb < 8; ++kb) {
            int h0 = kb * 32 + g4 * 8;
            U4 a;
            a.q = *(const uint4*)(smem + h_addr(n, h0));
            const uint8_t* p = wsb + WP2OFF + (size_t)(kb * 2) * 1024 + (size_t)l * 16;
            U4 bh, bl;
            bh.q = *(const uint4*)p;
            bl.q = *(const uint4*)(p + 1024);
            acc = __builtin_amdgcn_mfma_f32_16x16x32_bf16(a.s8, bh.s8, acc, 0, 0, 0);
            acc = __builtin_amdgcn_mfma_f32_16x16x32_bf16(a.s8, bl.s8, acc, 0, 0, 0);
        }
#pragma unroll
        for (int r = 0; r < 4; ++r) {
            int nn = w * 16 + g4 * 4 + r;
            *(float*)(smem + s_addr(nn, l15)) = acc[r];
        }
    }
    __syncthreads();

    // ---- policy softmax over 10 actions ----
    if (t < 32) {
        float v[10];
#pragma unroll
        for (int a2 = 0; a2 < 10; ++a2) v[a2] = *(const float*)(smem + s_addr(t, a2));
        float mx = v[0];
#pragma unroll
        for (int a2 = 1; a2 < 10; ++a2) mx = fmaxf(mx, v[a2]);
        float sum = 0.f;
#pragma unroll
        for (int a2 = 0; a2 < 10; ++a2) { v[a2] = __expf(v[a2] - mx); sum += v[a2]; }
        float inv = 1.0f / sum;
#pragma unroll
        for (int a2 = 0; a2 < 10; ++a2) *(float*)(smem + s_addr(t, a2)) = v[a2] * inv;
    }
    __syncthreads();

    for (int o = t; o < 320; o += 256) {
        int n = o / 10, a2 = o - n * 10;
        out_policy[(size_t)b * 320 + o] = *(const float*)(smem + s_addr(n, a2));
    }
}

}  // namespace

extern "C" void kernel_launch(void* const* d_in, const int* in_sizes, int n_in,
                              void* d_out, int out_size, void* d_ws, size_t ws_size,
                              hipStream_t stream) {
    const float* states = (const float*)d_in[0];
    const float* Wk1 = (const float*)d_in[1];
    const float* Wq1 = (const float*)d_in[2];
    const float* Wv1 = (const float*)d_in[3];
    const float* Wk2 = (const float*)d_in[4];
    const float* Wq2 = (const float*)d_in[5];
    const float* Wv2 = (const float*)d_in[6];
    const float* Wp1 = (const float*)d_in[7];
    const float* Wp2 = (const float*)d_in[8];

    const int B = in_sizes[0] / 4096;   // 8192

    uint8_t* wsb = (uint8_t*)d_ws;      // needs ~528 KB
    float* out        = (float*)d_out;
    float* out_policy = out;
    float* out_w1     = out_policy + (size_t)B * 320;
    float* out_w2     = out_w1 + (size_t)B * 1024;

    hipLaunchKernelGGL(prepack, dim3(264), dim3(64), 0, stream,
                       Wk1, Wq1, Wv1, Wk2, Wq2, Wv2, Wp1, Wp2, wsb);
    hipLaunchKernelGGL(fused_net, dim3(B), dim3(256), 0, stream,
                       states, wsb, out_policy, out_w1, out_w2);
}

// Round 5
// 350.366 us; speedup vs baseline: 1.3120x; 1.3120x over previous
//
#include <hip/hip_runtime.h>
#include <stdint.h>

namespace {

typedef __attribute__((ext_vector_type(8)))  short short8;   // 8 bf16
typedef __attribute__((ext_vector_type(16))) float f32x16;
typedef __attribute__((ext_vector_type(4)))  float f32x4;

union U4 {
    uint4    q;
    uint32_t u[4];
    uint16_t us[8];
    short8   s8;
};

constexpr float INV_SCALE = 0.08838834764831845f;  // 1/sqrt(128), BOTH attn blocks

// ---- workspace (weight fragment) layout, bytes ----
// per proj matrix: frags[(c*8+kb)*2 + hiLo][lane] of 16B; c=0..3, kb=0..7
constexpr size_t WSPROJ = 65536;            // 4*8*2*1024
constexpr size_t WP1OFF = 6 * WSPROJ;       // Wp1: c=0..7, kb=0..7 -> 131072 B
constexpr size_t WP2OFF = WP1OFF + 131072;  // Wp2 (16x16 frags): kb=0..7 -> 16384 B

// ---- LDS arena (53760 B -> 3 blocks/CU) ----
constexpr int K_OFF = 0;       // packed {hi|lo} u32 [32][128], swizzled, 16KB
constexpr int Q_OFF = 16384;   // packed {hi|lo} u32 [32][128], swizzled, 16KB
constexpr int V_OFF = 32768;   // VT packed u32 [128e][32m], swizzled, 16KB
constexpr int S_OFF = 49152;   // fp32 [32][36dw], 4608B
// ACT fp32 [32][128] (swizzled) aliases [0,16384)     = K region (dead when written)
// H   bf16 [32][256] (swizzled) aliases [16384,32768) = Q region (dead when written)

__device__ __forceinline__ int qk_addr(int base, int m, int e) {
    return base + ((m * 512 + e * 4) ^ ((m & 31) << 4));
}
__device__ __forceinline__ int vt_addr(int e, int m) {
    return V_OFF + ((e * 128 + m * 4) ^ ((e & 7) << 4));
}
__device__ __forceinline__ int s_addr(int n, int m) {
    return S_OFF + n * 144 + m * 4;
}
__device__ __forceinline__ int act_addr(int n, int d) {
    return ((n * 512 + d * 4) ^ ((n & 31) << 4));
}
__device__ __forceinline__ int h_addr(int n, int h) {
    return Q_OFF + ((n * 512 + h * 2) ^ ((n & 15) << 4));
}

__device__ __forceinline__ uint16_t f2bf_rne(float x) {  // round-to-nearest-even bf16
    uint32_t u = __float_as_uint(x);
    u += 0x7FFFu + ((u >> 16) & 1u);
    return (uint16_t)(u >> 16);
}

// split 8 fp32 -> (hi bf16x8, lo bf16x8); hi = trunc, lo = trunc(x - hi)
__device__ __forceinline__ void split8(float4 a, float4 b, short8& hi, short8& lo) {
    float xs[8] = {a.x, a.y, a.z, a.w, b.x, b.y, b.z, b.w};
    U4 h, l;
#pragma unroll
    for (int p = 0; p < 4; ++p) {
        uint32_t b0 = __float_as_uint(xs[2 * p]);
        uint32_t b1 = __float_as_uint(xs[2 * p + 1]);
        float r0 = xs[2 * p]     - __uint_as_float(b0 & 0xFFFF0000u);
        float r1 = xs[2 * p + 1] - __uint_as_float(b1 & 0xFFFF0000u);
        h.u[p] = __builtin_amdgcn_perm(b1, b0, 0x07060302u);                       // [hi(x1)|hi(x0)]
        l.u[p] = __builtin_amdgcn_perm(__float_as_uint(r1), __float_as_uint(r0), 0x07060302u);
    }
    hi = h.s8; lo = l.s8;
}

// 8 packed dwords {hi16|lo16} -> hi frag / lo frag
__device__ __forceinline__ void unpack8(const uint32_t* d, short8& hi, short8& lo) {
    U4 h, l;
#pragma unroll
    for (int p = 0; p < 4; ++p) {
        h.u[p] = __builtin_amdgcn_perm(d[2 * p + 1], d[2 * p], 0x07060302u);
        l.u[p] = __builtin_amdgcn_perm(d[2 * p + 1], d[2 * p], 0x05040100u);
    }
    hi = h.s8; lo = l.s8;
}

__device__ __forceinline__ uint32_t pack_hilo(float x) {
    uint32_t b = __float_as_uint(x);
    float r = x - __uint_as_float(b & 0xFFFF0000u);
    return __builtin_amdgcn_perm(b, __float_as_uint(r), 0x07060302u);  // [hi(x)|hi(r)]
}

// 32x128 GEMM col-tile c (K=128): acc[n][e] = sum_d A[n][d] * W[e][d], 3-term split
__device__ __forceinline__ f32x16 gemm32(const uint8_t* __restrict__ matbase, int c, int l,
                                         const short8* ahi, const short8* alo) {
    f32x16 acc = {0.f,0.f,0.f,0.f, 0.f,0.f,0.f,0.f, 0.f,0.f,0.f,0.f, 0.f,0.f,0.f,0.f};
#pragma unroll
    for (int kb = 0; kb < 8; ++kb) {
        const uint8_t* p = matbase + (size_t)((c * 8 + kb) * 2) * 1024 + (size_t)l * 16;
        U4 bh, bl;
        bh.q = *(const uint4*)p;
        bl.q = *(const uint4*)(p + 1024);
        acc = __builtin_amdgcn_mfma_f32_32x32x16_bf16(ahi[kb], bh.s8, acc, 0, 0, 0);
        acc = __builtin_amdgcn_mfma_f32_32x32x16_bf16(alo[kb], bh.s8, acc, 0, 0, 0);
        acc = __builtin_amdgcn_mfma_f32_32x32x16_bf16(ahi[kb], bl.s8, acc, 0, 0, 0);
    }
    return acc;
}

__device__ __forceinline__ void store_qk(char* smem, int base, int c, int l, const f32x16& acc) {
    const int e = c * 32 + (l & 31);
    const int half = l >> 5;
#pragma unroll
    for (int r = 0; r < 16; ++r) {
        int n = (r & 3) + 8 * (r >> 2) + 4 * half;   // verified 32x32 D mapping
        *(uint32_t*)(smem + qk_addr(base, n, e)) = pack_hilo(acc[r]);
    }
}

// -------- pre-pass: convert weights to fragment-ordered split-bf16 in d_ws --------
__global__ void prepack(const float* __restrict__ Wk1, const float* __restrict__ Wq1,
                        const float* __restrict__ Wv1, const float* __restrict__ Wk2,
                        const float* __restrict__ Wq2, const float* __restrict__ Wv2,
                        const float* __restrict__ Wp1, const float* __restrict__ Wp2,
                        uint8_t* __restrict__ wsb) {
    const int bid = blockIdx.x;
    const int l = threadIdx.x;
    float4 fa = make_float4(0.f, 0.f, 0.f, 0.f), fb = fa;
    uint8_t* dst;
    if (bid < 192) {                       // 6 proj matrices, 32x32 B-frags
        int m = bid >> 5, rem = bid & 31, c = rem >> 3, kb = rem & 7;
        const float* W = (m == 0) ? Wk1 : (m == 1) ? Wq1 : (m == 2) ? Wv1
                       : (m == 3) ? Wk2 : (m == 4) ? Wq2 : Wv2;
        int e  = c * 32 + (l & 31);        // B col on lane&31
        int d0 = kb * 16 + (l >> 5) * 8;   // k = 8*(l>>5)+i
        const float* src = W + e * 128 + d0;
        fa = *(const float4*)src;
        fb = *(const float4*)(src + 4);
        dst = wsb + (size_t)m * WSPROJ + (size_t)((c * 8 + kb) * 2) * 1024 + l * 16;
    } else if (bid < 256) {                // Wp1 [256][128]
        int idx = bid - 192, c = idx >> 3, kb = idx & 7;
        int e  = c * 32 + (l & 31);
        int d0 = kb * 16 + (l >> 5) * 8;
        const float* src = Wp1 + e * 128 + d0;
        fa = *(const float4*)src;
        fb = *(const float4*)(src + 4);
        dst = wsb + WP1OFF + (size_t)((c * 8 + kb) * 2) * 1024 + l * 16;
    } else {                               // Wp2 [10][256] -> 16x16 B-frags, cols 10..15 zero
        int kb = bid - 256;
        int a  = l & 15;
        int h0 = kb * 32 + ((l >> 4) & 3) * 8;
        if (a < 10) {
            const float* src = Wp2 + a * 256 + h0;
            fa = *(const float4*)src;
            fb = *(const float4*)(src + 4);
        }
        dst = wsb + WP2OFF + (size_t)(kb * 2) * 1024 + l * 16;
    }
    short8 hi, lo;
    split8(fa, fb, hi, lo);
    *(short8*)dst = hi;
    *(short8*)(dst + 1024) = lo;
}

// -------- main fused kernel: one batch per block, 4 waves ----
// NOTE: min-waves hint MUST stay at 2: (256,3) forced VGPR 116->84 and spilled
// the A-fragment arrays (hbm_bytes 1.5e8 -> 8.7e8, +110 us). LDS=53760 still
// gives 3 blocks/CU at VGPR<=128.
__global__ __launch_bounds__(256, 2)
void fused_net(const float* __restrict__ states, const uint8_t* __restrict__ wsb,
               float* __restrict__ out_policy, float* __restrict__ out_w1,
               float* __restrict__ out_w2) {
    __shared__ __align__(16) char smem[53760];

    const int b    = blockIdx.x;
    const int t    = threadIdx.x;
    const int w    = t >> 6;
    const int l    = t & 63;
    const int l31  = l & 31;
    const int half = l >> 5;
    const int l15  = l & 15;
    const int g4   = (l >> 4) & 3;

    // ---- A-frags of X straight from global (no staging), split once ----
    short8 ahi[8], alo[8];
    {
        const float* xrow = states + (size_t)b * 4096 + (size_t)l31 * 128;
#pragma unroll
        for (int kb = 0; kb < 8; ++kb) {
            int d0 = kb * 16 + half * 8;
            float4 fa = *(const float4*)(xrow + d0);
            float4 fb = *(const float4*)(xrow + d0 + 4);
            split8(fa, fb, ahi[kb], alo[kb]);
        }
    }

#pragma unroll 1
    for (int blk = 0; blk < 2; ++blk) {
        const uint8_t* wb = wsb + (size_t)(blk * 3) * WSPROJ;

        // ---- projections: wave w owns col-tile c=w of K, Q, V ----
        {
            f32x16 acc = gemm32(wb + 0 * WSPROJ, w, l, ahi, alo);
            store_qk(smem, K_OFF, w, l, acc);
        }
        {
            f32x16 acc = gemm32(wb + 1 * WSPROJ, w, l, ahi, alo);
            store_qk(smem, Q_OFF, w, l, acc);
        }
        {
            f32x16 acc = gemm32(wb + 2 * WSPROJ, w, l, ahi, alo);
            const int e = w * 32 + l31;
#pragma unroll
            for (int r = 0; r < 16; ++r) {
                int m = (r & 3) + 8 * (r >> 2) + 4 * half;
                *(uint32_t*)(smem + vt_addr(e, m)) = pack_hilo(acc[r]);
            }
        }
        __syncthreads();

        // ---- S = (Q K^T)*inv_scale: 4x 16x16 tiles, wave w -> (rb=w>>1, mb=w&1) ----
        {
            f32x4 s4 = {0.f, 0.f, 0.f, 0.f};
            const int rb = w >> 1, mb = w & 1;
            const int qrow = rb * 16 + l15;
            const int krow = mb * 16 + l15;
#pragma unroll
            for (int kb = 0; kb < 4; ++kb) {
                int e0 = kb * 32 + g4 * 8;
                uint32_t qd[8], kd[8];
                *(uint4*)&qd[0] = *(const uint4*)(smem + qk_addr(Q_OFF, qrow, e0));
                *(uint4*)&qd[4] = *(const uint4*)(smem + qk_addr(Q_OFF, qrow, e0 + 4));
                *(uint4*)&kd[0] = *(const uint4*)(smem + qk_addr(K_OFF, krow, e0));
                *(uint4*)&kd[4] = *(const uint4*)(smem + qk_addr(K_OFF, krow, e0 + 4));
                short8 qh, ql, kh, kl;
                unpack8(qd, qh, ql);
                unpack8(kd, kh, kl);
                s4 = __builtin_amdgcn_mfma_f32_16x16x32_bf16(qh, kh, s4, 0, 0, 0);
                s4 = __builtin_amdgcn_mfma_f32_16x16x32_bf16(ql, kh, s4, 0, 0, 0);
                s4 = __builtin_amdgcn_mfma_f32_16x16x32_bf16(qh, kl, s4, 0, 0, 0);
            }
#pragma unroll
            for (int r = 0; r < 4; ++r) {
                int n = rb * 16 + g4 * 4 + r;    // verified 16x16 D mapping
                *(float*)(smem + s_addr(n, krow)) = s4[r] * INV_SCALE;
            }
        }
        __syncthreads();

        // ---- softmax over m (wave 0: lane = row | half) ----
        if (t < 64) {
            const int n = l31;
            float4 v0 = *(const float4*)(smem + s_addr(n, half * 16));
            float4 v1 = *(const float4*)(smem + s_addr(n, half * 16 + 4));
            float4 v2 = *(const float4*)(smem + s_addr(n, half * 16 + 8));
            float4 v3 = *(const float4*)(smem + s_addr(n, half * 16 + 12));
            float vv[16] = {v0.x, v0.y, v0.z, v0.w, v1.x, v1.y, v1.z, v1.w,
                            v2.x, v2.y, v2.z, v2.w, v3.x, v3.y, v3.z, v3.w};
            float mx = vv[0];
#pragma unroll
            for (int i = 1; i < 16; ++i) mx = fmaxf(mx, vv[i]);
            mx = fmaxf(mx, __shfl_xor(mx, 32));
            float sum = 0.f;
#pragma unroll
            for (int i = 0; i < 16; ++i) { vv[i] = __expf(vv[i] - mx); sum += vv[i]; }
            sum += __shfl_xor(sum, 32);
            float inv = 1.0f / sum;
#pragma unroll
            for (int i = 0; i < 16; ++i) vv[i] *= inv;
            *(float4*)(smem + s_addr(n, half * 16))      = make_float4(vv[0], vv[1], vv[2], vv[3]);
            *(float4*)(smem + s_addr(n, half * 16 + 4))  = make_float4(vv[4], vv[5], vv[6], vv[7]);
            *(float4*)(smem + s_addr(n, half * 16 + 8))  = make_float4(vv[8], vv[9], vv[10], vv[11]);
            *(float4*)(smem + s_addr(n, half * 16 + 12)) = make_float4(vv[12], vv[13], vv[14], vv[15]);
        }
        __syncthreads();

        // ---- attention-weight output (coalesced) ----
        {
            float* outw = blk ? out_w2 : out_w1;
            int f = t * 4;
            int n = f >> 5, m0 = f & 31;
            float4 o = *(const float4*)(smem + s_addr(n, m0));
            *(float4*)(outw + (size_t)b * 1024 + f) = o;
        }

        // ---- PV: WAV[n][e] = sum_m P[n][m] V[m][e]; P 2-term, V 2-term, 3 MFMA ----
        {
            f32x16 pv = {0.f,0.f,0.f,0.f, 0.f,0.f,0.f,0.f, 0.f,0.f,0.f,0.f, 0.f,0.f,0.f,0.f};
            const int e = w * 32 + l31;
#pragma unroll
            for (int kb = 0; kb < 2; ++kb) {
                int m0 = kb * 16 + half * 8;
                float4 fa = *(const float4*)(smem + s_addr(l31, m0));
                float4 fb = *(const float4*)(smem + s_addr(l31, m0 + 4));
                short8 wh, wl;
                split8(fa, fb, wh, wl);
                uint32_t vd[8];
                *(uint4*)&vd[0] = *(const uint4*)(smem + vt_addr(e, m0));
                *(uint4*)&vd[4] = *(const uint4*)(smem + vt_addr(e, m0 + 4));
                short8 vh, vl;
                unpack8(vd, vh, vl);
                pv = __builtin_amdgcn_mfma_f32_32x32x16_bf16(wh, vh, pv, 0, 0, 0);
                pv = __builtin_amdgcn_mfma_f32_32x32x16_bf16(wl, vh, pv, 0, 0, 0);
                pv = __builtin_amdgcn_mfma_f32_32x32x16_bf16(wh, vl, pv, 0, 0, 0);
            }
            // ACT store aliases K region (dead since S-phase barrier); disjoint from S/VT,
            // so no barrier needed between PV-MFMA reads and this store.
            const int e2 = w * 32 + l31;
#pragma unroll
            for (int r = 0; r < 16; ++r) {
                int n = (r & 3) + 8 * (r >> 2) + 4 * half;
                *(float*)(smem + act_addr(n, e2)) = pv[r];
            }
        }
        __syncthreads();

        // ---- re-split A-frags from ACT (WAV for blk1 / NF for MLP) ----
#pragma unroll
        for (int kb = 0; kb < 8; ++kb) {
            int d0 = kb * 16 + half * 8;
            float4 fa = *(const float4*)(smem + act_addr(l31, d0));
            float4 fb = *(const float4*)(smem + act_addr(l31, d0 + 4));
            split8(fa, fb, ahi[kb], alo[kb]);
        }
        __syncthreads();   // ACT reads done before next blk's K-writes overwrite [0,16K)
    }

    // ---- MLP hidden: H = leaky_relu(NF @ Wp1^T) -> bf16 rne, aliases Q region ----
#pragma unroll
    for (int rep = 0; rep < 2; ++rep) {
        const int c = w + rep * 4;
        f32x16 acc = gemm32(wsb + WP1OFF, c, l, ahi, alo);
        const int hcol = c * 32 + l31;
#pragma unroll
        for (int r = 0; r < 16; ++r) {
            int n = (r & 3) + 8 * (r >> 2) + 4 * half;
            float x = acc[r];
            x = fmaxf(x, 0.01f * x);                      // leaky_relu
            *(uint16_t*)(smem + h_addr(n, hcol)) = f2bf_rne(x);
        }
    }
    __syncthreads();

    // ---- policy logits: 2x 16x16 tiles (waves 0,1), K=256, A=H(1-term), B=Wp2(hi+lo) ----
    if (w < 2) {
        f32x4 acc = {0.f, 0.f, 0.f, 0.f};
        const int n = w * 16 + l15;
#pragma unroll
        for (int kb = 0; kb < 8; ++kb) {
            int h0 = kb * 32 + g4 * 8;
            U4 a;
            a.q = *(const uint4*)(smem + h_addr(n, h0));
            const uint8_t* p = wsb + WP2OFF + (size_t)(kb * 2) * 1024 + (size_t)l * 16;
            U4 bh, bl;
            bh.q = *(const uint4*)p;
            bl.q = *(const uint4*)(p + 1024);
            acc = __builtin_amdgcn_mfma_f32_16x16x32_bf16(a.s8, bh.s8, acc, 0, 0, 0);
            acc = __builtin_amdgcn_mfma_f32_16x16x32_bf16(a.s8, bl.s8, acc, 0, 0, 0);
        }
#pragma unroll
        for (int r = 0; r < 4; ++r) {
            int nn = w * 16 + g4 * 4 + r;
            *(float*)(smem + s_addr(nn, l15)) = acc[r];
        }
    }
    __syncthreads();

    // ---- policy softmax over 10 actions ----
    if (t < 32) {
        float v[10];
#pragma unroll
        for (int a2 = 0; a2 < 10; ++a2) v[a2] = *(const float*)(smem + s_addr(t, a2));
        float mx = v[0];
#pragma unroll
        for (int a2 = 1; a2 < 10; ++a2) mx = fmaxf(mx, v[a2]);
        float sum = 0.f;
#pragma unroll
        for (int a2 = 0; a2 < 10; ++a2) { v[a2] = __expf(v[a2] - mx); sum += v[a2]; }
        float inv = 1.0f / sum;
#pragma unroll
        for (int a2 = 0; a2 < 10; ++a2) *(float*)(smem + s_addr(t, a2)) = v[a2] * inv;
    }
    __syncthreads();

    for (int o = t; o < 320; o += 256) {
        int n = o / 10, a2 = o - n * 10;
        out_policy[(size_t)b * 320 + o] = *(const float*)(smem + s_addr(n, a2));
    }
}

}  // namespace

extern "C" void kernel_launch(void* const* d_in, const int* in_sizes, int n_in,
                              void* d_out, int out_size, void* d_ws, size_t ws_size,
                              hipStream_t stream) {
    const float* states = (const float*)d_in[0];
    const float* Wk1 = (const float*)d_in[1];
    const float* Wq1 = (const float*)d_in[2];
    const float* Wv1 = (const float*)d_in[3];
    const float* Wk2 = (const float*)d_in[4];
    const float* Wq2 = (const float*)d_in[5];
    const float* Wv2 = (const float*)d_in[6];
    const float* Wp1 = (const float*)d_in[7];
    const float* Wp2 = (const float*)d_in[8];

    const int B = in_sizes[0] / 4096;   // 8192

    uint8_t* wsb = (uint8_t*)d_ws;      // needs ~528 KB
    float* out        = (float*)d_out;
    float* out_policy = out;
    float* out_w1     = out_policy + (size_t)B * 320;
    float* out_w2     = out_w1 + (size_t)B * 1024;

    hipLaunchKernelGGL(prepack, dim3(264), dim3(64), 0, stream,
                       Wk1, Wq1, Wv1, Wk2, Wq2, Wv2, Wp1, Wp2, wsb);
    hipLaunchKernelGGL(fused_net, dim3(B), dim3(256), 0, stream,
                       states, wsb, out_policy, out_w1, out_w2);
}

// Round 6
// 311.337 us; speedup vs baseline: 1.4765x; 1.1254x over previous
//
#include <hip/hip_runtime.h>
#include <stdint.h>

namespace {

typedef __attribute__((ext_vector_type(8)))  short short8;   // 8 bf16
typedef __attribute__((ext_vector_type(16))) float f32x16;
typedef __attribute__((ext_vector_type(4)))  float f32x4;

union U4 {
    uint4    q;
    uint32_t u[4];
    uint16_t us[8];
    short8   s8;
};

constexpr float INV_SCALE = 0.08838834764831845f;  // 1/sqrt(128), BOTH attn blocks

// ---- workspace (weight fragment) layout, bytes ----
constexpr size_t WSPROJ = 65536;            // 4c*8kb*2(hi,lo)*1024
constexpr size_t WP1OFF = 6 * WSPROJ;       // Wp1: c=0..7, kb=0..7 -> 131072 B
constexpr size_t WP2OFF = WP1OFF + 131072;  // Wp2 (16x16 frags): kb=0..7 -> 16384 B

// ---- LDS arena (53760 B -> 3 blocks/CU) ----
constexpr int K_OFF = 0;       // K packed {hi|lo} u32 [32][128], swizzled, 16KB; H aliases (bf16 [32][256])
constexpr int Q_OFF = 16384;   // Q/ACT packed {hi|lo} u32 [32][128], swizzled, 16KB (ping-pong)
constexpr int V_OFF = 32768;   // VT packed u32 [128e][32m], swizzled, 16KB
constexpr int S_OFF = 49152;   // fp32 [32][36dw], 4608B

__device__ __forceinline__ int qk_addr(int base, int m, int e) {
    return base + ((m * 512 + e * 4) ^ ((m & 31) << 4));
}
__device__ __forceinline__ int vt_addr(int e, int m) {
    return V_OFF + ((e * 128 + m * 4) ^ ((e & 7) << 4));
}
__device__ __forceinline__ int s_addr(int n, int m) {
    return S_OFF + n * 144 + m * 4;
}
__device__ __forceinline__ int h_addr(int n, int h) {   // H in dead K region
    return K_OFF + ((n * 512 + h * 2) ^ ((n & 15) << 4));
}

__device__ __forceinline__ uint16_t f2bf_rne(float x) {
    uint32_t u = __float_as_uint(x);
    u += 0x7FFFu + ((u >> 16) & 1u);
    return (uint16_t)(u >> 16);
}

// split 8 fp32 -> (hi bf16x8, lo bf16x8); hi = trunc, lo = trunc(x - hi)
__device__ __forceinline__ void split8(float4 a, float4 b, short8& hi, short8& lo) {
    float xs[8] = {a.x, a.y, a.z, a.w, b.x, b.y, b.z, b.w};
    U4 h, l;
#pragma unroll
    for (int p = 0; p < 4; ++p) {
        uint32_t b0 = __float_as_uint(xs[2 * p]);
        uint32_t b1 = __float_as_uint(xs[2 * p + 1]);
        float r0 = xs[2 * p]     - __uint_as_float(b0 & 0xFFFF0000u);
        float r1 = xs[2 * p + 1] - __uint_as_float(b1 & 0xFFFF0000u);
        h.u[p] = __builtin_amdgcn_perm(b1, b0, 0x07060302u);
        l.u[p] = __builtin_amdgcn_perm(__float_as_uint(r1), __float_as_uint(r0), 0x07060302u);
    }
    hi = h.s8; lo = l.s8;
}

// 8 packed dwords {hi16|lo16} -> hi frag / lo frag
__device__ __forceinline__ void unpack8(const uint32_t* d, short8& hi, short8& lo) {
    U4 h, l;
#pragma unroll
    for (int p = 0; p < 4; ++p) {
        h.u[p] = __builtin_amdgcn_perm(d[2 * p + 1], d[2 * p], 0x07060302u);
        l.u[p] = __builtin_amdgcn_perm(d[2 * p + 1], d[2 * p], 0x05040100u);
    }
    hi = h.s8; lo = l.s8;
}

__device__ __forceinline__ uint32_t pack_hilo(float x) {
    uint32_t b = __float_as_uint(x);
    float r = x - __uint_as_float(b & 0xFFFF0000u);
    return __builtin_amdgcn_perm(b, __float_as_uint(r), 0x07060302u);  // [hi(x)|hi(r)]
}

// 32x128 GEMM col-tile c (K=128): acc[n][e] = sum_d A[n][d]*W[e][d], 3-term split.
// A read per-kb from packed-ACT in LDS (Q region) -> no persistent A registers.
__device__ __forceinline__ f32x16 gemm32(const char* smem, const uint8_t* __restrict__ matbase,
                                         int c, int l) {
    f32x16 acc = {0.f,0.f,0.f,0.f, 0.f,0.f,0.f,0.f, 0.f,0.f,0.f,0.f, 0.f,0.f,0.f,0.f};
    const int n = l & 31, half = l >> 5;
#pragma unroll
    for (int kb = 0; kb < 8; ++kb) {
        const int d0 = kb * 16 + half * 8;
        uint32_t ad[8];
        *(uint4*)&ad[0] = *(const uint4*)(smem + qk_addr(Q_OFF, n, d0));
        *(uint4*)&ad[4] = *(const uint4*)(smem + qk_addr(Q_OFF, n, d0 + 4));
        short8 ah, al;
        unpack8(ad, ah, al);
        const uint8_t* p = matbase + (size_t)((c * 8 + kb) * 2) * 1024 + (size_t)l * 16;
        U4 bh, bl;
        bh.q = *(const uint4*)p;
        bl.q = *(const uint4*)(p + 1024);
        acc = __builtin_amdgcn_mfma_f32_32x32x16_bf16(ah, bh.s8, acc, 0, 0, 0);
        acc = __builtin_amdgcn_mfma_f32_32x32x16_bf16(al, bh.s8, acc, 0, 0, 0);
        acc = __builtin_amdgcn_mfma_f32_32x32x16_bf16(ah, bl.s8, acc, 0, 0, 0);
    }
    return acc;
}

__device__ __forceinline__ void store_qk(char* smem, int base, int c, int l, const f32x16& acc) {
    const int e = c * 32 + (l & 31);
    const int half = l >> 5;
#pragma unroll
    for (int r = 0; r < 16; ++r) {
        int n = (r & 3) + 8 * (r >> 2) + 4 * half;   // verified 32x32 D mapping
        *(uint32_t*)(smem + qk_addr(base, n, e)) = pack_hilo(acc[r]);
    }
}

// -------- pre-pass: convert weights to fragment-ordered split-bf16 in d_ws --------
__global__ void prepack(const float* __restrict__ Wk1, const float* __restrict__ Wq1,
                        const float* __restrict__ Wv1, const float* __restrict__ Wk2,
                        const float* __restrict__ Wq2, const float* __restrict__ Wv2,
                        const float* __restrict__ Wp1, const float* __restrict__ Wp2,
                        uint8_t* __restrict__ wsb) {
    const int bid = blockIdx.x;
    const int l = threadIdx.x;
    float4 fa = make_float4(0.f, 0.f, 0.f, 0.f), fb = fa;
    uint8_t* dst;
    if (bid < 192) {                       // 6 proj matrices, 32x32 B-frags
        int m = bid >> 5, rem = bid & 31, c = rem >> 3, kb = rem & 7;
        const float* W = (m == 0) ? Wk1 : (m == 1) ? Wq1 : (m == 2) ? Wv1
                       : (m == 3) ? Wk2 : (m == 4) ? Wq2 : Wv2;
        int e  = c * 32 + (l & 31);
        int d0 = kb * 16 + (l >> 5) * 8;
        const float* src = W + e * 128 + d0;
        fa = *(const float4*)src;
        fb = *(const float4*)(src + 4);
        dst = wsb + (size_t)m * WSPROJ + (size_t)((c * 8 + kb) * 2) * 1024 + l * 16;
    } else if (bid < 256) {                // Wp1 [256][128]
        int idx = bid - 192, c = idx >> 3, kb = idx & 7;
        int e  = c * 32 + (l & 31);
        int d0 = kb * 16 + (l >> 5) * 8;
        const float* src = Wp1 + e * 128 + d0;
        fa = *(const float4*)src;
        fb = *(const float4*)(src + 4);
        dst = wsb + WP1OFF + (size_t)((c * 8 + kb) * 2) * 1024 + l * 16;
    } else {                               // Wp2 [10][256] -> 16x16 B-frags, cols 10..15 zero
        int kb = bid - 256;
        int a  = l & 15;
        int h0 = kb * 32 + ((l >> 4) & 3) * 8;
        if (a < 10) {
            const float* src = Wp2 + a * 256 + h0;
            fa = *(const float4*)src;
            fb = *(const float4*)(src + 4);
        }
        dst = wsb + WP2OFF + (size_t)(kb * 2) * 1024 + l * 16;
    }
    short8 hi, lo;
    split8(fa, fb, hi, lo);
    *(short8*)dst = hi;
    *(short8*)(dst + 1024) = lo;
}

// -------- main fused kernel: one batch per block, 4 waves, 3 blocks/CU --------
// A-fragments live in LDS (packed hi/lo), not registers: round-5 counters showed
// VGPR(116)+AGPR total > 170 capped residency at 2 blocks/CU. (256,3) is safe now
// because natural pressure is ~half; spill tripwire = hbm_bytes >> 1.5e8.
__global__ __launch_bounds__(256, 3)
void fused_net(const float* __restrict__ states, const uint8_t* __restrict__ wsb,
               float* __restrict__ out_policy, float* __restrict__ out_w1,
               float* __restrict__ out_w2) {
    __shared__ __align__(16) char smem[53760];

    const int b    = blockIdx.x;
    const int t    = threadIdx.x;
    const int w    = t >> 6;
    const int l    = t & 63;
    const int l31  = l & 31;
    const int half = l >> 5;
    const int l15  = l & 15;
    const int g4   = (l >> 4) & 3;

    // ---- stage X packed hi/lo into ACT (Q region), coalesced ----
    {
        const float* src = states + (size_t)b * 4096;
#pragma unroll
        for (int r = 0; r < 4; ++r) {
            int flat = (t + 256 * r) * 4;
            int n = flat >> 7, d0 = flat & 127;
            float4 v = *(const float4*)(src + flat);
            uint4 p;
            p.x = pack_hilo(v.x); p.y = pack_hilo(v.y);
            p.z = pack_hilo(v.z); p.w = pack_hilo(v.w);
            *(uint4*)(smem + qk_addr(Q_OFF, n, d0)) = p;
        }
    }
    __syncthreads();

#pragma unroll 1
    for (int blk = 0; blk < 2; ++blk) {
        const uint8_t* wb = wsb + (size_t)(blk * 3) * WSPROJ;

        // ---- projections: Q first (held in regs), then K and V (stored) ----
        f32x16 qacc = gemm32(smem, wb + 1 * WSPROJ, w, l);
        {
            f32x16 acc = gemm32(smem, wb + 0 * WSPROJ, w, l);
            store_qk(smem, K_OFF, w, l, acc);
        }
        {
            f32x16 acc = gemm32(smem, wb + 2 * WSPROJ, w, l);
            const int e = w * 32 + l31;
#pragma unroll
            for (int r = 0; r < 16; ++r) {
                int m = (r & 3) + 8 * (r >> 2) + 4 * half;
                *(uint32_t*)(smem + vt_addr(e, m)) = pack_hilo(acc[r]);
            }
        }
        __syncthreads();                       // all ACT reads + K/VT writes done
        store_qk(smem, Q_OFF, w, l, qacc);     // overwrite ACT with Q
        __syncthreads();

        // ---- S = (Q K^T)*inv_scale: 4x 16x16 tiles, wave w -> (rb=w>>1, mb=w&1) ----
        {
            f32x4 s4 = {0.f, 0.f, 0.f, 0.f};
            const int rb = w >> 1, mb = w & 1;
            const int qrow = rb * 16 + l15;
            const int krow = mb * 16 + l15;
#pragma unroll
            for (int kb = 0; kb < 4; ++kb) {
                int e0 = kb * 32 + g4 * 8;
                uint32_t qd[8], kd[8];
                *(uint4*)&qd[0] = *(const uint4*)(smem + qk_addr(Q_OFF, qrow, e0));
                *(uint4*)&qd[4] = *(const uint4*)(smem + qk_addr(Q_OFF, qrow, e0 + 4));
                *(uint4*)&kd[0] = *(const uint4*)(smem + qk_addr(K_OFF, krow, e0));
                *(uint4*)&kd[4] = *(const uint4*)(smem + qk_addr(K_OFF, krow, e0 + 4));
                short8 qh, ql, kh, kl;
                unpack8(qd, qh, ql);
                unpack8(kd, kh, kl);
                s4 = __builtin_amdgcn_mfma_f32_16x16x32_bf16(qh, kh, s4, 0, 0, 0);
                s4 = __builtin_amdgcn_mfma_f32_16x16x32_bf16(ql, kh, s4, 0, 0, 0);
                s4 = __builtin_amdgcn_mfma_f32_16x16x32_bf16(qh, kl, s4, 0, 0, 0);
            }
#pragma unroll
            for (int r = 0; r < 4; ++r) {
                int n = rb * 16 + g4 * 4 + r;    // verified 16x16 D mapping
                *(float*)(smem + s_addr(n, krow)) = s4[r] * INV_SCALE;
            }
        }
        __syncthreads();

        // ---- softmax over m (wave 0: lane = row | half) ----
        if (t < 64) {
            const int n = l31;
            float4 v0 = *(const float4*)(smem + s_addr(n, half * 16));
            float4 v1 = *(const float4*)(smem + s_addr(n, half * 16 + 4));
            float4 v2 = *(const float4*)(smem + s_addr(n, half * 16 + 8));
            float4 v3 = *(const float4*)(smem + s_addr(n, half * 16 + 12));
            float vv[16] = {v0.x, v0.y, v0.z, v0.w, v1.x, v1.y, v1.z, v1.w,
                            v2.x, v2.y, v2.z, v2.w, v3.x, v3.y, v3.z, v3.w};
            float mx = vv[0];
#pragma unroll
            for (int i = 1; i < 16; ++i) mx = fmaxf(mx, vv[i]);
            mx = fmaxf(mx, __shfl_xor(mx, 32));
            float sum = 0.f;
#pragma unroll
            for (int i = 0; i < 16; ++i) { vv[i] = __expf(vv[i] - mx); sum += vv[i]; }
            sum += __shfl_xor(sum, 32);
            float inv = 1.0f / sum;
#pragma unroll
            for (int i = 0; i < 16; ++i) vv[i] *= inv;
            *(float4*)(smem + s_addr(n, half * 16))      = make_float4(vv[0], vv[1], vv[2], vv[3]);
            *(float4*)(smem + s_addr(n, half * 16 + 4))  = make_float4(vv[4], vv[5], vv[6], vv[7]);
            *(float4*)(smem + s_addr(n, half * 16 + 8))  = make_float4(vv[8], vv[9], vv[10], vv[11]);
            *(float4*)(smem + s_addr(n, half * 16 + 12)) = make_float4(vv[12], vv[13], vv[14], vv[15]);
        }
        __syncthreads();

        // ---- attention-weight output (coalesced) ----
        {
            float* outw = blk ? out_w2 : out_w1;
            int f = t * 4;
            int n = f >> 5, m0 = f & 31;
            float4 o = *(const float4*)(smem + s_addr(n, m0));
            *(float4*)(outw + (size_t)b * 1024 + f) = o;
        }

        // ---- PV: ACT'[n][e] = sum_m P[n][m] V[m][e]; pack result into Q region ----
        {
            f32x16 pv = {0.f,0.f,0.f,0.f, 0.f,0.f,0.f,0.f, 0.f,0.f,0.f,0.f, 0.f,0.f,0.f,0.f};
            const int e = w * 32 + l31;
#pragma unroll
            for (int kb = 0; kb < 2; ++kb) {
                int m0 = kb * 16 + half * 8;
                float4 fa = *(const float4*)(smem + s_addr(l31, m0));
                float4 fb = *(const float4*)(smem + s_addr(l31, m0 + 4));
                short8 wh, wl;
                split8(fa, fb, wh, wl);
                uint32_t vd[8];
                *(uint4*)&vd[0] = *(const uint4*)(smem + vt_addr(e, m0));
                *(uint4*)&vd[4] = *(const uint4*)(smem + vt_addr(e, m0 + 4));
                short8 vh, vl;
                unpack8(vd, vh, vl);
                pv = __builtin_amdgcn_mfma_f32_32x32x16_bf16(wh, vh, pv, 0, 0, 0);
                pv = __builtin_amdgcn_mfma_f32_32x32x16_bf16(wl, vh, pv, 0, 0, 0);
                pv = __builtin_amdgcn_mfma_f32_32x32x16_bf16(wh, vl, pv, 0, 0, 0);
            }
            // Q region dead since S-phase barrier; store packed ACT' there.
            store_qk(smem, Q_OFF, w, l, pv);
        }
        __syncthreads();
    }

    // ---- MLP hidden: H = leaky_relu(NF @ Wp1^T) -> bf16 rne into dead K region ----
#pragma unroll
    for (int rep = 0; rep < 2; ++rep) {
        const int c = w + rep * 4;
        f32x16 acc = gemm32(smem, wsb + WP1OFF, c, l);
        const int hcol = c * 32 + l31;
#pragma unroll
        for (int r = 0; r < 16; ++r) {
            int n = (r & 3) + 8 * (r >> 2) + 4 * half;
            float x = acc[r];
            x = fmaxf(x, 0.01f * x);                      // leaky_relu
            *(uint16_t*)(smem + h_addr(n, hcol)) = f2bf_rne(x);
        }
    }
    __syncthreads();

    // ---- policy logits: 2x 16x16 tiles (waves 0,1), K=256, A=H(1-term), B=Wp2(hi+lo) ----
    if (w < 2) {
        f32x4 acc = {0.f, 0.f, 0.f, 0.f};
        const int n = w * 16 + l15;
#pragma unroll
        for (int kb = 0; kb < 8; ++kb) {
            int h0 = kb * 32 + g4 * 8;
            U4 a;
            a.q = *(const uint4*)(smem + h_addr(n, h0));
            const uint8_t* p = wsb + WP2OFF + (size_t)(kb * 2) * 1024 + (size_t)l * 16;
            U4 bh, bl;
            bh.q = *(const uint4*)p;
            bl.q = *(const uint4*)(p + 1024);
            acc = __builtin_amdgcn_mfma_f32_16x16x32_bf16(a.s8, bh.s8, acc, 0, 0, 0);
            acc = __builtin_amdgcn_mfma_f32_16x16x32_bf16(a.s8, bl.s8, acc, 0, 0, 0);
        }
#pragma unroll
        for (int r = 0; r < 4; ++r) {
            int nn = w * 16 + g4 * 4 + r;
            *(float*)(smem + s_addr(nn, l15)) = acc[r];
        }
    }
    __syncthreads();

    // ---- policy softmax over 10 actions ----
    if (t < 32) {
        float v[10];
#pragma unroll
        for (int a2 = 0; a2 < 10; ++a2) v[a2] = *(const float*)(smem + s_addr(t, a2));
        float mx = v[0];
#pragma unroll
        for (int a2 = 1; a2 < 10; ++a2) mx = fmaxf(mx, v[a2]);
        float sum = 0.f;
#pragma unroll
        for (int a2 = 0; a2 < 10; ++a2) { v[a2] = __expf(v[a2] - mx); sum += v[a2]; }
        float inv = 1.0f / sum;
#pragma unroll
        for (int a2 = 0; a2 < 10; ++a2) *(float*)(smem + s_addr(t, a2)) = v[a2] * inv;
    }
    __syncthreads();

    for (int o = t; o < 320; o += 256) {
        int n = o / 10, a2 = o - n * 10;
        out_policy[(size_t)b * 320 + o] = *(const float*)(smem + s_addr(n, a2));
    }
}

}  // namespace

extern "C" void kernel_launch(void* const* d_in, const int* in_sizes, int n_in,
                              void* d_out, int out_size, void* d_ws, size_t ws_size,
                              hipStream_t stream) {
    const float* states = (const float*)d_in[0];
    const float* Wk1 = (const float*)d_in[1];
    const float* Wq1 = (const float*)d_in[2];
    const float* Wv1 = (const float*)d_in[3];
    const float* Wk2 = (const float*)d_in[4];
    const float* Wq2 = (const float*)d_in[5];
    const float* Wv2 = (const float*)d_in[6];
    const float* Wp1 = (const float*)d_in[7];
    const float* Wp2 = (const float*)d_in[8];

    const int B = in_sizes[0] / 4096;   // 8192

    uint8_t* wsb = (uint8_t*)d_ws;      // needs ~528 KB
    float* out        = (float*)d_out;
    float* out_policy = out;
    float* out_w1     = out_policy + (size_t)B * 320;
    float* out_w2     = out_w1 + (size_t)B * 1024;

    hipLaunchKernelGGL(prepack, dim3(264), dim3(64), 0, stream,
                       Wk1, Wq1, Wv1, Wk2, Wq2, Wv2, Wp1, Wp2, wsb);
    hipLaunchKernelGGL(fused_net, dim3(B), dim3(256), 0, stream,
                       states, wsb, out_policy, out_w1, out_w2);
}